// Round 1
// baseline (150.801 us; speedup 1.0000x reference)
//
#include <hip/hip_runtime.h>

// SLAYER SNN forward, MI355X.
// Pipeline: K1 conv1(5x5,p2)+sumpool4 folded into one 9x9 stride-4 conv ->
//           K2 PSP+spike scan (T=100, in-place) ->
//           K3 conv2(3x3,p1)+sumpool2 folded into 4x4 stride-2 conv ->
//           K4 PSP+spike scan (in-place) -> K5 dense einsum.
// All fp32 (threshold semantics too sensitive for bf16; no fp32 MFMA anyway).
// Workspace: u1 = 100*16384 floats (in-place becomes s1), u2 = 100*8192 (becomes s2).

#define DECAY 0.9048374180359595f   // exp(-1/10), rounds to same fp32 as np

// ---------------- K1: conv1 + pool1 as 9x9 stride-4 conv ----------------
// grid (100, 64) = (t, n); block 256. Output u1[t*16384 + n*256 + c*64 + i*8 + j].
__global__ __launch_bounds__(256) void k1_conv1(const float* __restrict__ x,
        const float* __restrict__ w1, const float* __restrict__ wp1,
        float* __restrict__ u1) {
    const int t = blockIdx.x, n = blockIdx.y;
    // x tile with halo 2: rows/cols -2..34 (37), pitch 40 (16B-aligned rows,
    // 160B row stride -> 8-bank rotation). 2*37*40 = 2960 floats.
    __shared__ float xs[2 * 37 * 40];
    // folded weights W2[c][cin][e][f], pitch 12 over f for aligned float4.
    __shared__ float wl[4 * 2 * 9 * 12];   // 864
    const int tid = threadIdx.x;

    for (int idx = tid; idx < 2 * 37 * 40; idx += 256) xs[idx] = 0.f;

    const float p1 = wp1[0];
    for (int idx = tid; idx < 864; idx += 256) {
        const int f = idx % 12;
        const int rem = idx / 12;        // (c*2+cin)*9 + e
        const int e = rem % 9;
        const int cc = rem / 9;          // c*2+cin
        float s = 0.f;
        if (f < 9) {
            int alo = e - 3; if (alo < 0) alo = 0;
            int ahi = e;     if (ahi > 4) ahi = 4;
            int blo = f - 3; if (blo < 0) blo = 0;
            int bhi = f;     if (bhi > 4) bhi = 4;
            for (int a = alo; a <= ahi; ++a)
                for (int b = blo; b <= bhi; ++b)
                    s += w1[cc * 25 + a * 5 + b];
        }
        wl[idx] = s * p1;
    }
    __syncthreads();

    // stage frame (2048 floats, contiguous) into padded LDS
    const float4* xf = (const float4*)(x + ((size_t)n * 100 + t) * 2048);
    for (int m = tid; m < 512; m += 256) {
        float4 v = xf[m];
        const int li = 4 * m;
        const int cin = li >> 10;
        const int row = (li >> 5) & 31;
        const int col = li & 31;
        float* d = &xs[(cin * 37 + row + 2) * 40 + col + 2];
        d[0] = v.x; d[1] = v.y; d[2] = v.z; d[3] = v.w;   // 8B-aligned pair writes
    }
    __syncthreads();

    // lane map: 4 c-channels share (i,j) -> x reads broadcast 4-way in-wave
    const int c   = (tid >> 4) & 3;
    const int pos = (tid & 15) | ((tid >> 6) << 4);   // 0..63
    const int i0 = pos >> 3, j0 = pos & 7;

    float acc = 0.f;
    #pragma unroll
    for (int cin = 0; cin < 2; ++cin) {
        const float* xbase = &xs[(cin * 37 + 4 * i0) * 40 + 4 * j0]; // 16B aligned
        const float* wbase = &wl[(c * 2 + cin) * 108];
        #pragma unroll
        for (int e = 0; e < 9; ++e) {
            const float* xr = xbase + e * 40;
            const float* wr = wbase + e * 12;
            const float4 xa = *(const float4*)xr;
            const float4 xb = *(const float4*)(xr + 4);
            const float  xc = xr[8];
            const float4 wa = *(const float4*)wr;
            const float4 wb = *(const float4*)(wr + 4);
            const float  wc = wr[8];
            acc += xa.x * wa.x + xa.y * wa.y + xa.z * wa.z + xa.w * wa.w
                 + xb.x * wb.x + xb.y * wb.y + xb.z * wb.z + xb.w * wb.w
                 + xc * wc;
        }
    }
    u1[(size_t)t * 16384 + n * 256 + c * 64 + pos] = acc;
}

// ---------------- K2/K4: PSP + spike scan, in-place ----------------
// one thread per neuron column; 10-deep load batches keep VMEM in flight.
__global__ __launch_bounds__(256) void k_scan(float* __restrict__ u, int stride) {
    const int id = blockIdx.x * 256 + threadIdx.x;
    const float a = DECAY;
    float psp = 0.f, r = 0.f;
    float* p = u + id;
    #pragma unroll 1
    for (int t0 = 0; t0 < 100; t0 += 10) {
        float v[10];
        #pragma unroll
        for (int k = 0; k < 10; ++k) v[k] = p[(size_t)(t0 + k) * stride];
        #pragma unroll
        for (int k = 0; k < 10; ++k) {
            psp = a * psp + v[k];
            const float vv = psp - r;
            const float s = (vv >= 1.f) ? 1.f : 0.f;
            r = a * (r + s);
            p[(size_t)(t0 + k) * stride] = s;
        }
    }
}

// ---------------- K3: conv2 + pool2 as 4x4 stride-2 conv ----------------
// grid (100, 64); block 128. Output u2[t*8192 + n*128 + c2*16 + i*4 + j].
__global__ __launch_bounds__(128) void k3_conv2(const float* __restrict__ s1,
        const float* __restrict__ w2, const float* __restrict__ wp2,
        float* __restrict__ u2) {
    const int t = blockIdx.x, n = blockIdx.y;
    __shared__ float ss[4 * 10 * 10];      // halo 1: rows/cols -1..8
    __shared__ float wl[4 * 4 * 4 * 8];    // [cin][e][f][c2] -> c2 contiguous (bank-clean)
    const int tid = threadIdx.x;

    for (int idx = tid; idx < 400; idx += 128) ss[idx] = 0.f;

    const float p2 = wp2[0];
    for (int idx = tid; idx < 512; idx += 128) {
        const int c2 = idx & 7;
        const int f  = (idx >> 3) & 3;
        const int e  = (idx >> 5) & 3;
        const int cin = idx >> 7;
        float s = 0.f;
        int alo = e - 1; if (alo < 0) alo = 0;
        int ahi = e;     if (ahi > 2) ahi = 2;
        int blo = f - 1; if (blo < 0) blo = 0;
        int bhi = f;     if (bhi > 2) bhi = 2;
        for (int aa = alo; aa <= ahi; ++aa)
            for (int bb = blo; bb <= bhi; ++bb)
                s += w2[((c2 * 4 + cin) * 3 + aa) * 3 + bb];
        wl[idx] = s * p2;
    }
    __syncthreads();

    const float* fr = s1 + (size_t)t * 16384 + n * 256;
    for (int m = tid; m < 256; m += 128) {
        const int cin = m >> 6, row = (m >> 3) & 7, col = m & 7;
        ss[(cin * 10 + row + 1) * 10 + col + 1] = fr[m];
    }
    __syncthreads();

    // 8 c2-channels share (i,j) -> x reads broadcast 8-way in-wave
    const int c2  = (tid >> 3) & 7;
    const int pos = (tid & 7) | ((tid >> 6) << 3);   // 0..15
    const int i0 = pos >> 2, j0 = pos & 3;

    float acc = 0.f;
    #pragma unroll
    for (int cin = 0; cin < 4; ++cin) {
        #pragma unroll
        for (int e = 0; e < 4; ++e) {
            const float* xr = &ss[(cin * 10 + 2 * i0 + e) * 10 + 2 * j0];
            const float* wr = &wl[((cin * 4 + e) * 4) * 8 + c2];
            #pragma unroll
            for (int f = 0; f < 4; ++f)
                acc += xr[f] * wr[f * 8];
        }
    }
    u2[(size_t)t * 8192 + n * 128 + c2 * 16 + pos] = acc;
}

// ---------------- K5: dense einsum, one wave per (n,t) ----------------
__global__ __launch_bounds__(256) void k5_dense(const float* __restrict__ s2,
        const float* __restrict__ lw, float* __restrict__ out) {
    const int w = blockIdx.x * 4 + (threadIdx.x >> 6);   // 0..6399
    const int l = threadIdx.x & 63;
    const int n = w / 100, t = w % 100;
    const float* base = s2 + (size_t)t * 8192 + n * 128;
    const float sa = base[l], sb = base[64 + l];
    float a0 = sa * lw[l]       + sb * lw[64 + l];
    float a1 = sa * lw[128 + l] + sb * lw[192 + l];
    #pragma unroll
    for (int off = 32; off > 0; off >>= 1) {
        a0 += __shfl_down(a0, off);
        a1 += __shfl_down(a1, off);
    }
    if (l == 0) {
        out[n * 200 + t * 2]     = a0;
        out[n * 200 + t * 2 + 1] = a1;
    }
}

extern "C" void kernel_launch(void* const* d_in, const int* in_sizes, int n_in,
                              void* d_out, int out_size, void* d_ws, size_t ws_size,
                              hipStream_t stream) {
    const float* x   = (const float*)d_in[0];
    const float* w1  = (const float*)d_in[1];
    const float* w2  = (const float*)d_in[2];
    const float* lw  = (const float*)d_in[3];
    const float* wp1 = (const float*)d_in[4];
    const float* wp2 = (const float*)d_in[5];

    float* u1 = (float*)d_ws;            // 100*16384 = 1,638,400 floats (becomes s1 in-place)
    float* u2 = u1 + 1638400;            // 100*8192  =   819,200 floats (becomes s2 in-place)
    float* out = (float*)d_out;          // (64,100,2)

    dim3 g(100, 64);
    k1_conv1<<<g, 256, 0, stream>>>(x, w1, wp1, u1);
    k_scan<<<64, 256, 0, stream>>>(u1, 16384);
    k3_conv2<<<g, 128, 0, stream>>>(u1, w2, wp2, u2);
    k_scan<<<32, 256, 0, stream>>>(u2, 8192);
    k5_dense<<<1600, 256, 0, stream>>>(u2, lw, out);
}